// Round 1
// baseline (468.281 us; speedup 1.0000x reference)
//
#include <hip/hip_runtime.h>

// LIF Euler integration, one thread per row (B rows, L=400 steps).
//
// Forward math is EXACTLY (proven: straight-through estimator is a bitwise
// no-op in fp32, sigmoid never affects output bits):
//   v = (v - v/20.0f) + I[t];  s = (v >= 1.0f);  out[t] = s;  v = s ? 0 : v;
// All ops are IEEE correctly-rounded fp32 (default hipcc, no fast-math),
// matching the numpy reference bit-for-bit.

#define LIF_L 400
#define LIF_NV (LIF_L / 4)   // 100 float4 per row; row stride 1600 B is 16B-aligned

__global__ __launch_bounds__(256) void lif_kernel(const float* __restrict__ I,
                                                  float* __restrict__ out,
                                                  int nrows) {
    const int row = blockIdx.x * 256 + threadIdx.x;
    if (row >= nrows) return;

    const float4* __restrict__ in4 = reinterpret_cast<const float4*>(I) + (size_t)row * LIF_NV;
    float4* __restrict__ out4      = reinterpret_cast<float4*>(out)     + (size_t)row * LIF_NV;

    float v = 0.0f;

#pragma unroll 4
    for (int j = 0; j < LIF_NV; ++j) {
        const float4 x = in4[j];
        float4 s;

        // elem 0
        v = (v - v / 20.0f) + x.x;
        {
            const bool sp = (v >= 1.0f);
            s.x = sp ? 1.0f : 0.0f;
            v   = sp ? 0.0f : v;
        }
        // elem 1
        v = (v - v / 20.0f) + x.y;
        {
            const bool sp = (v >= 1.0f);
            s.y = sp ? 1.0f : 0.0f;
            v   = sp ? 0.0f : v;
        }
        // elem 2
        v = (v - v / 20.0f) + x.z;
        {
            const bool sp = (v >= 1.0f);
            s.z = sp ? 1.0f : 0.0f;
            v   = sp ? 0.0f : v;
        }
        // elem 3
        v = (v - v / 20.0f) + x.w;
        {
            const bool sp = (v >= 1.0f);
            s.w = sp ? 1.0f : 0.0f;
            v   = sp ? 0.0f : v;
        }

        out4[j] = s;
    }
}

extern "C" void kernel_launch(void* const* d_in, const int* in_sizes, int n_in,
                              void* d_out, int out_size, void* d_ws, size_t ws_size,
                              hipStream_t stream) {
    const float* I = (const float*)d_in[0];
    float* out = (float*)d_out;
    const int nrows = in_sizes[0] / LIF_L;   // B = 131072

    const int block = 256;
    const int grid = (nrows + block - 1) / block;  // 512 blocks
    lif_kernel<<<grid, block, 0, stream>>>(I, out, nrows);
}

// Round 2
// 439.925 us; speedup vs baseline: 1.0645x; 1.0645x over previous
//
#include <hip/hip_runtime.h>

// LIF Euler integration, one thread per row (B=131072 rows, L=400 steps).
//
// Forward math is EXACTLY:
//   v = (v - v/20.0f) + I[t];  s = (v >= 1.0f);  out[t] = s;  v = s ? 0 : v;
// (straight-through estimator + sigmoid are bitwise no-ops in fp32 forward).
//
// v/20.0f is computed with the Markstein FMA sequence (q0 = v*RN(1/20);
// e = fma(-20,q0,v); t = fma(e,RN(1/20),q0)), which is provably correctly
// rounded for all normal fp32 v (round-to-nearest theorem) -> bit-identical
// to hardware division, 3 ops instead of ~10.
//
// Structure: depth-3 software-pipelined ring of 4-float4 chunks (16 steps
// per chunk). Load for chunk c+3 issues right after chunk c is consumed,
// giving ~2 chunk-computes (~500-700 cy) of memory lead per wave. Occupancy
// is thread-capped (2 waves/SIMD), so the ~70 VGPRs are free.

#define LIF_L 400
#define LIF_NV 100   // float4 per row (row stride 1600 B, 16B-aligned)
#define CHUNK 4      // float4 per chunk = 16 timesteps = 64 B
#define NCHUNK 25    // chunks per row (3*8 + 1)

__global__ __launch_bounds__(256) void lif_kernel(const float* __restrict__ I,
                                                  float* __restrict__ out,
                                                  int nrows) {
    const int row = blockIdx.x * 256 + threadIdx.x;
    if (row >= nrows) return;

    const float4* __restrict__ in4 = reinterpret_cast<const float4*>(I) + (size_t)row * LIF_NV;
    float4* __restrict__ out4      = reinterpret_cast<float4*>(out)     + (size_t)row * LIF_NV;

    constexpr float RCP = 0.05f;   // RN(1/20)
    float v = 0.0f;

    float4 bA[CHUNK], bB[CHUNK], bC[CHUNK];

    auto loadChunk = [&](float4* buf, int c) {
#pragma unroll
        for (int j = 0; j < CHUNK; ++j) buf[j] = in4[c * CHUNK + j];
    };

    auto step = [&](float x) -> float {
        const float p0 = v * RCP;
        const float e  = __builtin_fmaf(-20.0f, p0, v);
        const float t  = __builtin_fmaf(e, RCP, p0);   // t == RN(v/20)
        v = (v - t) + x;
        const bool sp = (v >= 1.0f);
        const float s = sp ? 1.0f : 0.0f;
        v = sp ? 0.0f : v;
        return s;
    };

    auto doChunk = [&](float4* buf, int c) {
#pragma unroll
        for (int j = 0; j < CHUNK; ++j) {
            const float4 x = buf[j];
            float4 s;
            s.x = step(x.x);
            s.y = step(x.y);
            s.z = step(x.z);
            s.w = step(x.w);
            out4[c * CHUNK + j] = s;
        }
    };

    loadChunk(bA, 0);
    loadChunk(bB, 1);
    loadChunk(bC, 2);

    for (int k = 0; k < 8; ++k) {
        const int c = 3 * k;
        doChunk(bA, c);     loadChunk(bA, c + 3);
        doChunk(bB, c + 1); if (k < 7) loadChunk(bB, c + 4);
        doChunk(bC, c + 2); if (k < 7) loadChunk(bC, c + 5);
    }
    doChunk(bA, 24);   // chunk 24 was loaded at k == 7
}

extern "C" void kernel_launch(void* const* d_in, const int* in_sizes, int n_in,
                              void* d_out, int out_size, void* d_ws, size_t ws_size,
                              hipStream_t stream) {
    const float* I = (const float*)d_in[0];
    float* out = (float*)d_out;
    const int nrows = in_sizes[0] / LIF_L;   // B = 131072

    const int block = 256;
    const int grid = (nrows + block - 1) / block;  // 512 blocks
    lif_kernel<<<grid, block, 0, stream>>>(I, out, nrows);
}

// Round 3
// 436.035 us; speedup vs baseline: 1.0740x; 1.0089x over previous
//
#include <hip/hip_runtime.h>

// LIF Euler integration, one thread per row (B=131072 rows, L=400 steps).
//
// Forward math is EXACTLY:
//   v = (v - v/20.0f) + I[t];  s = (v >= 1.0f);  out[t] = s;  v = s ? 0 : v;
// (straight-through estimator + sigmoid are bitwise no-ops in fp32 forward;
//  v/20.0f via Markstein FMA sequence == correctly-rounded division, proven
//  bit-exact in round 2, absmax 0).
//
// Performance structure: the compiler sank round-2's C++ prefetch ring back
// to just-in-time loads (VGPR_Count=32 proved it), leaving the kernel
// latency-bound at 24% HBM. Here ALL VMEM is inline asm so it cannot be
// re-scheduled:
//   - depth-5 ring of 16-timestep chunks: 20 global_load_dwordx4 in flight
//     continuously per wave (8 waves/CU -> enough MLP to saturate HBM)
//   - counted s_waitcnt vmcnt(N) per chunk (N=32 steady; ramped at the ends;
//     N counts loads AND the asm stores interleaved in issue order)
//   - rule-18 closed by dataflow: the waitcnt asm carries the consumed
//     chunk's registers as "+v" operands, so uses are data-ordered after it
//   - asm-store WAR hazard closed by holding store-data registers "+v"
//     through the wait that provably drains that store (SD=6 ring + final
//     vmcnt(0) holder for the last 6 chunks' data)

typedef float f32x4 __attribute__((ext_vector_type(4)));

#define LIF_L 400

__global__ __launch_bounds__(256) void lif_kernel(const float* __restrict__ I,
                                                  float* __restrict__ out,
                                                  int nrows) {
    const int row = blockIdx.x * 256 + threadIdx.x;
    if (row >= nrows) return;

    const float* __restrict__ ib = I + (size_t)row * LIF_L;
    float*       __restrict__ ob = out + (size_t)row * LIF_L;

    constexpr int NC = 25;  // chunks of 16 timesteps (4 x float4)
    constexpr int D  = 5;   // load ring depth (prefetch distance)
    constexpr int SD = 6;   // store-data ring depth

    f32x4 ld[D][4];
    f32x4 sv[SD][4] = {};

    // Prologue: issue loads for chunks 0..D-1 (20 loads in flight).
    #pragma unroll
    for (int c = 0; c < D; ++c) {
        #pragma unroll
        for (int j = 0; j < 4; ++j)
            asm volatile("global_load_dwordx4 %0, %1, off offset:%c2"
                         : "=v"(ld[c][j])
                         : "v"(ib), "i"(c * 64 + j * 16));
    }

    // W[c]: #ops (4 per load/store group) issued AFTER chunk c's last load.
    // Issue order: [L0..L4] then per iter c: {wait, compute, S_c, L_{c+5}}.
    // Steady state: newer-than-L_c = iters c-4..c-1 = 4*8 = 32.
    // Ramp up: 16+4c for c<5. Ramp down: missing loads after c=19.
    // W[c] also (stricter) drains S_{c-6} before its sv slot is rewritten.
    constexpr int W[NC] = {16, 20, 24, 28, 32,
                           32, 32, 32, 32, 32, 32, 32, 32,
                           32, 32, 32, 32, 32, 32, 32, 32,
                           28, 24, 20, 16};

    constexpr float RCP = 0.05f;  // RN(1/20)
    float v = 0.0f;

    #pragma unroll
    for (int c = 0; c < NC; ++c) {
        const int ls = c % D;
        const int ss = c % SD;

        // Wait until chunk c's loads have landed (and S_{c-6} has drained).
        // "+v" ties make all later uses data-dependent on this asm.
        asm volatile("s_waitcnt vmcnt(%c8)"
                     : "+v"(ld[ls][0]), "+v"(ld[ls][1]),
                       "+v"(ld[ls][2]), "+v"(ld[ls][3]),
                       "+v"(sv[ss][0]), "+v"(sv[ss][1]),
                       "+v"(sv[ss][2]), "+v"(sv[ss][3])
                     : "i"(W[c]));

        // 16 timesteps, bit-exact LIF update.
        #pragma unroll
        for (int j = 0; j < 4; ++j) {
            const f32x4 x = ld[ls][j];
            f32x4 s;
            #pragma unroll
            for (int e = 0; e < 4; ++e) {
                const float p0 = v * RCP;
                const float er = __builtin_fmaf(-20.0f, p0, v);
                const float t  = __builtin_fmaf(er, RCP, p0);  // == RN(v/20)
                v = (v - t) + x[e];
                const bool sp = (v >= 1.0f);
                s[e] = sp ? 1.0f : 0.0f;
                v = sp ? 0.0f : v;
            }
            sv[ss][j] = s;
        }

        // Store chunk c (fire-and-forget; data regs protected by sv ring).
        #pragma unroll
        for (int j = 0; j < 4; ++j)
            asm volatile("global_store_dwordx4 %0, %1, off offset:%c2"
                         :: "v"(ob), "v"(sv[ss][j]), "i"(c * 64 + j * 16)
                         : "memory");

        // Refill the ring: issue loads for chunk c+D.
        if (c + D < NC) {
            #pragma unroll
            for (int j = 0; j < 4; ++j)
                asm volatile("global_load_dwordx4 %0, %1, off offset:%c2"
                             : "=v"(ld[ls][j])
                             : "v"(ib), "i"((c + D) * 64 + j * 16));
        }
    }

    // Keep the last SD chunks' store-data registers alive until all VMEM
    // drains (their protecting waits fall past the end of the loop).
    asm volatile("s_waitcnt vmcnt(0)"
                 : "+v"(sv[0][0]), "+v"(sv[0][1]), "+v"(sv[0][2]), "+v"(sv[0][3]),
                   "+v"(sv[1][0]), "+v"(sv[1][1]), "+v"(sv[1][2]), "+v"(sv[1][3]),
                   "+v"(sv[2][0]), "+v"(sv[2][1]), "+v"(sv[2][2]), "+v"(sv[2][3]),
                   "+v"(sv[3][0]), "+v"(sv[3][1]), "+v"(sv[3][2]), "+v"(sv[3][3]),
                   "+v"(sv[4][0]), "+v"(sv[4][1]), "+v"(sv[4][2]), "+v"(sv[4][3]),
                   "+v"(sv[5][0]), "+v"(sv[5][1]), "+v"(sv[5][2]), "+v"(sv[5][3]));
}

extern "C" void kernel_launch(void* const* d_in, const int* in_sizes, int n_in,
                              void* d_out, int out_size, void* d_ws, size_t ws_size,
                              hipStream_t stream) {
    const float* I = (const float*)d_in[0];
    float* out = (float*)d_out;
    const int nrows = in_sizes[0] / LIF_L;  // B = 131072

    const int block = 256;
    const int grid = (nrows + block - 1) / block;  // 512 blocks
    lif_kernel<<<grid, block, 0, stream>>>(I, out, nrows);
}

// Round 4
// 395.674 us; speedup vs baseline: 1.1835x; 1.1020x over previous
//
#include <hip/hip_runtime.h>

// LIF Euler integration, B=131072 rows x L=400 steps, bit-exact forward:
//   v = (v - v/20.0f) + I[t];  s = (v >= 1.0f);  out[t] = s;  v = s ? 0 : v;
// (straight-through + sigmoid are forward no-ops; v/20 via Markstein FMA ==
//  correctly-rounded division; absmax 0 in rounds 1-3.)
//
// R1-R3 all plateaued at ~2 TB/s regardless of per-wave MLP depth: the
// per-thread-row layout makes every VMEM instruction touch 64 distinct
// 128-B lines (1600-B lane stride), exhausting per-CU line-tracking.
// This version decouples IO from compute via LDS staging:
//   - IO role: thread (rr=tid/4, p=tid%4) moves rows rr+64i, piece p ->
//     16 fully-used, never-straddling 64-B segments per wave instruction
//   - compute role: thread owns row tid, reads its 64-B chunk from LDS
//   - LDS [256][4] float4 with slot-XOR swizzle (slot ^ ((row>>1)&3)):
//     all ds_read/ds_write_b128 patterns conflict-free (8 lanes/4-bank grp)
//   - input double-buffered, output single-buffered: 48 KB, 2 blocks/CU
//   - global ops in asm with counted vmcnt (steady vmcnt(8), 2-chunk load
//     lead), raw s_barrier + lgkmcnt(0) so no compiler vmcnt(0) drain,
//     "+v" dataflow ties for load consumption + store-reg WAR protection

typedef float f32x4 __attribute__((ext_vector_type(4)));

#define LIF_L 400

__global__ __launch_bounds__(256) void lif_kernel(const float* __restrict__ I,
                                                  float* __restrict__ out) {
    const int tid = threadIdx.x;
    const int base_row = blockIdx.x * 256;

    __shared__ f32x4 inb[2][256][4];   // 32 KB, chunk c in inb[c&1]
    __shared__ f32x4 outb[256][4];     // 16 KB spike staging

    // IO role: rows rr+64i (i=0..3), 16-B piece p of each 64-B chunk.
    const int rr = tid >> 2;
    const int p  = tid & 3;
    const int pp = p ^ ((rr >> 1) & 3);     // physical LDS slot (swizzled)
    // compute role: own row = tid
    const int swt = (tid >> 1) & 3;

    const float* ibp[4];
    float* obp[4];
    #pragma unroll
    for (int i = 0; i < 4; ++i) {
        const size_t r = (size_t)(base_row + rr + 64 * i);
        ibp[i] = I   + r * LIF_L + p * 4;
        obp[i] = out + r * LIF_L + p * 4;
    }

    f32x4 gl[2][4];          // in-flight load sets (chunk k -> set k&1)
    f32x4 so[2][4] = {};     // store-data sets (chunk c -> set c&1)

    // ---- prologue: L(0)->gl[0], L(1)->gl[1]; stage chunk 0; L(2)->gl[0]
    #pragma unroll
    for (int i = 0; i < 4; ++i)
        asm volatile("global_load_dwordx4 %0, %1, off offset:0"
                     : "=v"(gl[0][i]) : "v"(ibp[i]));
    #pragma unroll
    for (int i = 0; i < 4; ++i)
        asm volatile("global_load_dwordx4 %0, %1, off offset:64"
                     : "=v"(gl[1][i]) : "v"(ibp[i]));
    asm volatile("s_waitcnt vmcnt(4)"   // L(0) landed (L(1) may remain)
                 : "+v"(gl[0][0]), "+v"(gl[0][1]), "+v"(gl[0][2]), "+v"(gl[0][3]));
    #pragma unroll
    for (int i = 0; i < 4; ++i)
        inb[0][rr + 64 * i][pp] = gl[0][i];
    #pragma unroll
    for (int i = 0; i < 4; ++i)
        asm volatile("global_load_dwordx4 %0, %1, off offset:128"
                     : "=v"(gl[0][i]) : "v"(ibp[i]));
    asm volatile("s_waitcnt lgkmcnt(0)\n\ts_barrier" ::: "memory");

    // vmcnt values: drain L(c+1) (consumed now) and S(c-2) (store regs
    // recycled this iter). FIFO per iter: [waitC, L(c+3)] ... [S(c)].
    constexpr int W[25] = {4, 8, 8, 8, 8, 8, 8, 8, 8, 8, 8, 8, 8,
                           8, 8, 8, 8, 8, 8, 8, 8, 8, 8, 4, 4};

    constexpr float RCP = 0.05f;   // RN(1/20)
    float v = 0.0f;

    #pragma unroll
    for (int c = 0; c < 25; ++c) {
        const int cb = c & 1;
        const int nb = cb ^ 1;

        // ---- A: read own row's chunk, compute 16 bit-exact LIF steps ----
        f32x4 xs[4], sp[4];
        #pragma unroll
        for (int j = 0; j < 4; ++j)
            xs[j] = inb[cb][tid][j ^ swt];
        #pragma unroll
        for (int j = 0; j < 4; ++j) {
            #pragma unroll
            for (int e = 0; e < 4; ++e) {
                const float q0 = v * RCP;
                const float er = __builtin_fmaf(-20.0f, q0, v);
                const float t  = __builtin_fmaf(er, RCP, q0);  // == RN(v/20)
                v = (v - t) + xs[j][e];
                const bool spk = (v >= 1.0f);
                sp[j][e] = spk ? 1.0f : 0.0f;
                v = spk ? 0.0f : v;
            }
        }

        // ---- barrier1: chunk c-1's outb readers are done ----
        asm volatile("s_waitcnt lgkmcnt(0)\n\ts_barrier" ::: "memory");

        // ---- C: stage spikes; consume L(c+1); refill ring with L(c+3) ----
        #pragma unroll
        for (int j = 0; j < 4; ++j)
            outb[tid][j ^ swt] = sp[j];

        if (c < 24) {
            asm volatile("s_waitcnt vmcnt(%c8)"
                         : "+v"(gl[nb][0]), "+v"(gl[nb][1]),
                           "+v"(gl[nb][2]), "+v"(gl[nb][3]),
                           "+v"(so[cb][0]), "+v"(so[cb][1]),
                           "+v"(so[cb][2]), "+v"(so[cb][3])
                         : "i"(W[c]));
            #pragma unroll
            for (int i = 0; i < 4; ++i)
                inb[nb][rr + 64 * i][pp] = gl[nb][i];
            if (c <= 21) {
                #pragma unroll
                for (int i = 0; i < 4; ++i)
                    asm volatile("global_load_dwordx4 %0, %1, off offset:%c2"
                                 : "=v"(gl[nb][i])
                                 : "v"(ibp[i]), "i"((c + 3) * 64));
            }
        } else {
            asm volatile("s_waitcnt vmcnt(4)"   // drain S(22): recycle so[0]
                         : "+v"(so[0][0]), "+v"(so[0][1]),
                           "+v"(so[0][2]), "+v"(so[0][3]));
        }

        // ---- barrier2: chunk c's spikes staged, chunk c+1 staged ----
        asm volatile("s_waitcnt lgkmcnt(0)\n\ts_barrier" ::: "memory");

        // ---- E: coalesced store of chunk c ----
        #pragma unroll
        for (int i = 0; i < 4; ++i)
            so[cb][i] = outb[rr + 64 * i][pp];
        #pragma unroll
        for (int i = 0; i < 4; ++i)
            asm volatile("global_store_dwordx4 %1, %0, off offset:%c2"
                         : "+v"(so[cb][i])
                         : "v"(obp[i]), "i"(c * 64) : "memory");
    }

    // Drain all stores before endpgm; hold last store-data regs live.
    asm volatile("s_waitcnt vmcnt(0)"
                 : "+v"(so[0][0]), "+v"(so[0][1]), "+v"(so[0][2]), "+v"(so[0][3]),
                   "+v"(so[1][0]), "+v"(so[1][1]), "+v"(so[1][2]), "+v"(so[1][3]));
}

extern "C" void kernel_launch(void* const* d_in, const int* in_sizes, int n_in,
                              void* d_out, int out_size, void* d_ws, size_t ws_size,
                              hipStream_t stream) {
    const float* I = (const float*)d_in[0];
    float* out = (float*)d_out;
    const int nrows = in_sizes[0] / LIF_L;  // 131072
    const int grid = nrows / 256;           // 512 blocks, exact

    lif_kernel<<<grid, 256, 0, stream>>>(I, out);
}